// Round 5
// baseline (770.332 us; speedup 1.0000x reference)
//
#include <hip/hip_runtime.h>
#include <math.h>

// Problem constants
constexpr int N_TOKENS = 8192;
constexpr int D_MODEL  = 4096;
constexpr int N_EXP    = 256;

// Tile: 64 tokens x 128 experts per block, grid (128, 2) = 256 blocks.
constexpr int BM = 64;
constexpr int BE = 128;
constexpr int BK = 32;              // K per chunk = MFMA K
constexpr int NC = D_MODEL / BK;    // 128 chunks

// ws B layout: [chunk][g8: 8 groups of 32 experts][plane hi/lo][32exp x 32k swizzled]
constexpr int WS_PLANE = 32 * 32;        // 1024 ushorts (2 KB)
constexpr int WS_GRP   = 2 * WS_PLANE;   // 2048
constexpr int WS_CHUNK = 8 * WS_GRP;     // 16384 (32 KB)
constexpr size_t WSB_USHORTS = (size_t)NC * WS_CHUNK;          // 2M ushorts = 4 MB
constexpr size_t G_OFF_BYTES = WSB_USHORTS * sizeof(unsigned short);
constexpr size_t WS_NEED = G_OFF_BYTES + (size_t)N_TOKENS * 4 * 16;  // + 512 KB side buf

// gate kernel LDS: 8 waves x 3 bufs x 2048 ushorts = 96 KB (epilogue Ct overlays)
constexpr int W_STRIDE = 3 * 2048;       // per-wave staging stride (ushorts)
constexpr size_t LDS_BYTES = 8 * W_STRIDE * sizeof(unsigned short);  // 98304

typedef __attribute__((ext_vector_type(8))) short short8;
typedef __attribute__((ext_vector_type(4))) float f32x4;
typedef unsigned int u32;
typedef const __attribute__((address_space(1))) u32* gas_ptr;
typedef __attribute__((address_space(3))) u32* las_ptr;

static __device__ __forceinline__ unsigned short f2bf(float x) {
    union { float f; unsigned u; } v; v.f = x;
    unsigned r = v.u + 0x7fffu + ((v.u >> 16) & 1u);   // RNE
    return (unsigned short)(r >> 16);
}
static __device__ __forceinline__ float bf2f(unsigned short s) {
    union { unsigned u; float f; } v; v.u = ((unsigned)s) << 16;
    return v.f;
}
static __device__ __forceinline__ unsigned fbits(float x) {
    union { float f; unsigned u; } v; v.f = x; return v.u;
}
static __device__ __forceinline__ float bitsf(unsigned u) {
    union { unsigned u; float f; } v; v.u = u; return v.f;
}

// ---- W fp32 -> bf16 hi/lo planes, chunk-major, granule-swizzled ----
__global__ __launch_bounds__(256) void convert_w(
    const float* __restrict__ W, unsigned short* __restrict__ wsB)
{
    const int id   = blockIdx.x * 256 + threadIdx.x;   // [0, 131072)
    const int c    = id >> 10;
    const int rem  = id & 1023;
    const int e    = rem >> 2;
    const int slot = rem & 3;
    const int kq   = slot ^ ((e >> 2) & 3);            // logical k-granule

    const float* src = W + (size_t)e * D_MODEL + c * BK + kq * 8;
    const float4 x0 = *(const float4*)src;
    const float4 x1 = *(const float4*)(src + 4);
    const float xs[8] = {x0.x, x0.y, x0.z, x0.w, x1.x, x1.y, x1.z, x1.w};
    short8 vh, vl;
    #pragma unroll
    for (int j = 0; j < 8; ++j) {
        const unsigned short h = f2bf(xs[j]);
        vh[j] = (short)h;
        vl[j] = (short)f2bf(xs[j] - bf2f(h));
    }
    unsigned short* dst = wsB + (size_t)c * WS_CHUNK + (e >> 5) * WS_GRP
                        + (e & 31) * 32 + slot * 8;
    *(short8*)dst              = vh;
    *(short8*)(dst + WS_PLANE) = vl;
}

// ---- barrier-free bf16x3 MFMA GEMM + logits + per-group top2 ----
__global__ __launch_bounds__(512, 2) void gate_fused(
    const float* __restrict__ H, const unsigned short* __restrict__ wsB,
    float* __restrict__ logits, float4* __restrict__ G)
{
    extern __shared__ unsigned short lds[];

    const int t      = threadIdx.x;
    const int L      = t & 63;
    const int w      = t >> 6;          // wave 0..7
    const int mh     = w >> 2;          // token half (32 tokens)
    const int eq     = w & 3;           // expert quarter (32 experts)
    const int lane16 = L & 15;
    const int g4     = L >> 4;

    const int tok0 = blockIdx.x * BM;
    const int e0   = blockIdx.y * BE;
    const int g8   = blockIdx.y * 4 + eq;          // ws 32-expert group
    const int rowb = tok0 + mh * 32 + lane16;      // A fragment row base

    unsigned short* stg = lds + w * W_STRIDE;      // private staging (3 x 2048)

    f32x4 acc[2][2];
    #pragma unroll
    for (int mi = 0; mi < 2; ++mi)
        #pragma unroll
        for (int ni = 0; ni < 2; ++ni) acc[mi][ni] = (f32x4)0.0f;

    float4 araw[3][2][2];   // depth-3 A prefetch: [slot][mi][half]

    auto dmaB = [&](int c, int b) {
        const unsigned short* src = wsB + (size_t)c * WS_CHUNK + g8 * WS_GRP;
        unsigned short* dst = stg + b * 2048;
        #pragma unroll
        for (int p = 0; p < 2; ++p)
            #pragma unroll
            for (int h = 0; h < 2; ++h) {
                const int o = p * 1024 + h * 512;
                __builtin_amdgcn_global_load_lds(
                    (gas_ptr)(const void*)(src + o + L * 8),
                    (las_ptr)(void*)(dst + o), 16, 0, 0);
            }
    };
    auto loadA = [&](int c, int slot) {
        #pragma unroll
        for (int mi = 0; mi < 2; ++mi) {
            const float* p = H + (size_t)(rowb + mi * 16) * D_MODEL + c * BK + g4 * 8;
            araw[slot][mi][0] = *(const float4*)p;
            araw[slot][mi][1] = *(const float4*)(p + 4);
        }
    };

    // Prologue: order matters for the vmcnt protocol: d0, A0, d1, A1, A2
    dmaB(0, 0); loadA(0, 0);
    dmaB(1, 1); loadA(1, 1);
    loadA(2, 2);

    for (int c = 0; c < NC; ++c) {
        const int b  = c % 3;
        const int bn = (c + 2) % 3;

        // raw barrier: pace waves for L1 reuse; does NOT drain vmcnt.
        asm volatile("s_barrier" ::: "memory");
        // wait own dma(c) (+A(c), older). Steady state leaves 12 vmem in flight.
        if (c < NC - 2)       asm volatile("s_waitcnt vmcnt(12)" ::: "memory");
        else if (c == NC - 2) asm volatile("s_waitcnt vmcnt(8)"  ::: "memory");
        else                  asm volatile("s_waitcnt vmcnt(0)"  ::: "memory");

        // convert A(c): fp32 -> bf16 hi (trunc) + lo (residual, trunc)
        short8 ah[2], al[2];
        #pragma unroll
        for (int mi = 0; mi < 2; ++mi) {
            float xs[8];
            #pragma unroll
            for (int hf = 0; hf < 2; ++hf) {
                const float4 v = araw[b][mi][hf];
                xs[hf * 4 + 0] = v.x; xs[hf * 4 + 1] = v.y;
                xs[hf * 4 + 2] = v.z; xs[hf * 4 + 3] = v.w;
            }
            union { short8 s; u32 u[4]; } Hh, Ll;
            #pragma unroll
            for (int j = 0; j < 4; ++j) {
                const u32 b0 = fbits(xs[2 * j]), b1 = fbits(xs[2 * j + 1]);
                const u32 h0 = b0 & 0xFFFF0000u, h1 = b1 & 0xFFFF0000u;
                Hh.u[j] = (b0 >> 16) | h1;
                const float l0 = xs[2 * j] - bitsf(h0);
                const float l1 = xs[2 * j + 1] - bitsf(h1);
                Ll.u[j] = (fbits(l0) >> 16) | (fbits(l1) & 0xFFFF0000u);
            }
            ah[mi] = Hh.s; al[mi] = Ll.s;
        }

        // B fragments from private staging (XOR-swizzled, 2-way max = free)
        const unsigned short* bb = stg + b * 2048;
        short8 bh[2], bl[2];
        #pragma unroll
        for (int ni = 0; ni < 2; ++ni) {
            const int e_loc = ni * 16 + lane16;
            const int off   = e_loc * 32 + ((g4 ^ ((e_loc >> 2) & 3)) << 3);
            bh[ni] = *(const short8*)(bb + off);
            bl[ni] = *(const short8*)(bb + 1024 + off);
        }

        // deep prefetch: issue next dma + A while MFMAs run
        if (c + 2 < NC) dmaB(c + 2, bn);
        if (c + 3 < NC) loadA(c + 3, b);

        #pragma unroll
        for (int ni = 0; ni < 2; ++ni)
            #pragma unroll
            for (int mi = 0; mi < 2; ++mi) {
                acc[mi][ni] = __builtin_amdgcn_mfma_f32_16x16x32_bf16(ah[mi], bh[ni], acc[mi][ni], 0, 0, 0);
                acc[mi][ni] = __builtin_amdgcn_mfma_f32_16x16x32_bf16(ah[mi], bl[ni], acc[mi][ni], 0, 0, 0);
                acc[mi][ni] = __builtin_amdgcn_mfma_f32_16x16x32_bf16(al[mi], bh[ni], acc[mi][ni], 0, 0, 0);
            }
    }

    // ---- epilogue ----
    __syncthreads();                     // staging dead everywhere after this
    float* Ct = (float*)lds;             // [64][132] fp32 = 33.8 KB overlay
    #pragma unroll
    for (int mi = 0; mi < 2; ++mi)
        #pragma unroll
        for (int ni = 0; ni < 2; ++ni)
            #pragma unroll
            for (int r = 0; r < 4; ++r) {
                const int tk  = mh * 32 + mi * 16 + g4 * 4 + r;   // C/D row
                const int col = eq * 32 + ni * 16 + lane16;        // C/D col
                Ct[tk * 132 + col] = acc[mi][ni][r];
            }
    __syncthreads();

    // coalesced logits store: 64 rows x 128 cols = 2048 float4 / 512 thr
    #pragma unroll
    for (int i = 0; i < 4; ++i) {
        const int id = i * 512 + t;
        const int tk = id >> 5, j = id & 31;
        *(float4*)(logits + (size_t)(tok0 + tk) * N_EXP + e0 + j * 4) =
            *(const float4*)(Ct + tk * 132 + j * 4);
    }

    // per-(token, 64-expert-group) top2 on raw logits; sigmoid on winners only
    for (int it = 0; it < 16; ++it) {
        const int u  = w * 16 + it;
        const int tk = u >> 1, gl = u & 1;
        float v1 = Ct[tk * 132 + gl * 64 + L];
        int   i1 = e0 + gl * 64 + L;
        float v2 = -3.0e38f;
        int   i2 = i1;
        #pragma unroll
        for (int off = 1; off < 64; off <<= 1) {
            const float ov1 = __shfl_xor(v1, off);
            const int   oi1 = __shfl_xor(i1, off);
            const float ov2 = __shfl_xor(v2, off);
            const int   oi2 = __shfl_xor(i2, off);
            const bool o1_beats_m1 = (ov1 > v1) || (ov1 == v1 && oi1 < i1);
            if (o1_beats_m1) {
                const bool m1_beats_o2 = (v1 > ov2) || (v1 == ov2 && i1 < oi2);
                const float nv2 = m1_beats_o2 ? v1 : ov2;
                const int   ni2 = m1_beats_o2 ? i1 : oi2;
                v1 = ov1; i1 = oi1; v2 = nv2; i2 = ni2;
            } else {
                const bool o1_beats_m2 = (ov1 > v2) || (ov1 == v2 && oi1 < i2);
                v2 = o1_beats_m2 ? ov1 : v2;
                i2 = o1_beats_m2 ? oi1 : i2;
            }
        }
        if (L == 0) {
            const float s1 = 1.0f / (1.0f + expf(-v1));
            const float s2 = 1.0f / (1.0f + expf(-v2));
            float4 r; r.x = s1; r.y = s2; r.z = (float)i1; r.w = (float)i2;
            G[(size_t)(tok0 + tk) * 4 + (e0 >> 6) + gl] = r;
        }
    }
}

// ---- combine per-group top2 -> normalized weights + indices ----
__global__ __launch_bounds__(256) void combine(
    const float4* __restrict__ G,
    float* __restrict__ out_idx, float* __restrict__ out_w)
{
    const int tok = blockIdx.x * 256 + threadIdx.x;
    float4 g[4];
    #pragma unroll
    for (int i = 0; i < 4; ++i) g[i] = G[(size_t)tok * 4 + i];
    float sum = 0.0f;
    #pragma unroll
    for (int i = 0; i < 4; ++i) sum += g[i].x + g[i].y;
    const float sc = 2.5f / (sum + 1e-10f);
    float4 i01, i23, w01, w23;
    i01.x = g[0].z; i01.y = g[0].w; i01.z = g[1].z; i01.w = g[1].w;
    i23.x = g[2].z; i23.y = g[2].w; i23.z = g[3].z; i23.w = g[3].w;
    w01.x = g[0].x * sc; w01.y = g[0].y * sc; w01.z = g[1].x * sc; w01.w = g[1].y * sc;
    w23.x = g[2].x * sc; w23.y = g[2].y * sc; w23.z = g[3].x * sc; w23.w = g[3].y * sc;
    ((float4*)out_idx)[(size_t)tok * 2]     = i01;
    ((float4*)out_idx)[(size_t)tok * 2 + 1] = i23;
    ((float4*)out_w)[(size_t)tok * 2]       = w01;
    ((float4*)out_w)[(size_t)tok * 2 + 1]   = w23;
}

// ---------------- fallback (ws too small): fp32 VALU path ----------------
constexpr int FBM = 32;
constexpr int FBK = 16;
constexpr int FNC = D_MODEL / FBK;

__global__ __launch_bounds__(256) void gate_gemm_f32(
    const float* __restrict__ H, const float* __restrict__ W,
    float* __restrict__ logits)
{
    __shared__ float As[2][FBK][FBM + 4];
    __shared__ float Bs[2][FBK][N_EXP + 1];
    const int t = threadIdx.x, tx = t & 31, ty = t >> 5;
    const int tok0 = blockIdx.x * FBM, tokA = t >> 2, kqA = t & 3;
    float4 pa, pb[4];
    float acc[4][8];
    #pragma unroll
    for (int i = 0; i < 4; ++i)
        #pragma unroll
        for (int j = 0; j < 8; ++j) acc[i][j] = 0.0f;
    auto issue_loads = [&](int kc) {
        if (t < 128) pa = *(const float4*)(H + (size_t)(tok0 + tokA) * D_MODEL + kc + kqA * 4);
        #pragma unroll
        for (int j = 0; j < 4; ++j) {
            const int flat = t + 256 * j, e = flat >> 2, kq = flat & 3;
            pb[j] = *(const float4*)(W + (size_t)e * D_MODEL + kc + kq * 4);
        }
    };
    auto write_lds = [&](int buf) {
        if (t < 128) {
            As[buf][kqA * 4 + 0][tokA] = pa.x; As[buf][kqA * 4 + 1][tokA] = pa.y;
            As[buf][kqA * 4 + 2][tokA] = pa.z; As[buf][kqA * 4 + 3][tokA] = pa.w;
        }
        #pragma unroll
        for (int j = 0; j < 4; ++j) {
            const int flat = t + 256 * j, e = flat >> 2, kq = flat & 3;
            Bs[buf][kq * 4 + 0][e] = pb[j].x; Bs[buf][kq * 4 + 1][e] = pb[j].y;
            Bs[buf][kq * 4 + 2][e] = pb[j].z; Bs[buf][kq * 4 + 3][e] = pb[j].w;
        }
    };
    issue_loads(0); write_lds(0); __syncthreads();
    for (int c = 0; c < FNC; ++c) {
        const int buf = c & 1;
        if (c + 1 < FNC) issue_loads((c + 1) * FBK);
        #pragma unroll
        for (int k = 0; k < FBK; ++k) {
            const float4 av = *(const float4*)&As[buf][k][ty * 4];
            const float a[4] = {av.x, av.y, av.z, av.w};
            float b[8];
            #pragma unroll
            for (int j = 0; j < 8; ++j) b[j] = Bs[buf][k][tx + 32 * j];
            #pragma unroll
            for (int i = 0; i < 4; ++i)
                #pragma unroll
                for (int j = 0; j < 8; ++j) acc[i][j] = fmaf(a[i], b[j], acc[i][j]);
        }
        if (c + 1 < FNC) write_lds(buf ^ 1);
        __syncthreads();
    }
    #pragma unroll
    for (int i = 0; i < 4; ++i) {
        const size_t row = (size_t)(tok0 + ty * 4 + i) * N_EXP;
        #pragma unroll
        for (int j = 0; j < 8; ++j) logits[row + tx + 32 * j] = acc[i][j];
    }
}

__global__ __launch_bounds__(256) void topk_only(
    const float* __restrict__ logits,
    float* __restrict__ out_idx, float* __restrict__ out_w)
{
    const int token = blockIdx.x * 4 + (threadIdx.x >> 6);
    const int lane  = threadIdx.x & 63;
    const float4 x = *(const float4*)(logits + (size_t)token * N_EXP + lane * 4);
    float sc[4];
    sc[0] = 1.0f / (1.0f + expf(-x.x)); sc[1] = 1.0f / (1.0f + expf(-x.y));
    sc[2] = 1.0f / (1.0f + expf(-x.z)); sc[3] = 1.0f / (1.0f + expf(-x.w));
    float v1 = -1.0f, v2 = -1.0f; int i1 = 0, i2 = 0;
    #pragma unroll
    for (int j = 0; j < 4; ++j) {
        const int idx = lane * 4 + j;
        if (sc[j] > v1)      { v2 = v1; i2 = i1; v1 = sc[j]; i1 = idx; }
        else if (sc[j] > v2) { v2 = sc[j]; i2 = idx; }
    }
    #pragma unroll
    for (int offx = 1; offx < 16; offx <<= 1) {
        const float ov1 = __shfl_xor(v1, offx); const int oi1 = __shfl_xor(i1, offx);
        const float ov2 = __shfl_xor(v2, offx); const int oi2 = __shfl_xor(i2, offx);
        const bool o1_beats_m1 = (ov1 > v1) || (ov1 == v1 && oi1 < i1);
        if (o1_beats_m1) {
            const bool m1_beats_o2 = (v1 > ov2) || (v1 == ov2 && i1 < oi2);
            const float nv2 = m1_beats_o2 ? v1 : ov2;
            const int   ni2 = m1_beats_o2 ? i1 : oi2;
            v1 = ov1; i1 = oi1; v2 = nv2; i2 = ni2;
        } else {
            const bool o1_beats_m2 = (ov1 > v2) || (ov1 == v2 && oi1 < i2);
            v2 = o1_beats_m2 ? ov1 : v2; i2 = o1_beats_m2 ? oi1 : i2;
        }
    }
    float sum = 0.0f;
    #pragma unroll
    for (int g = 0; g < 4; ++g) sum += __shfl(v1, g * 16) + __shfl(v2, g * 16);
    const int src = ((lane >> 1) & 3) * 16;
    const float mv1 = __shfl(v1, src), mv2 = __shfl(v2, src);
    const int   mi1 = __shfl(i1, src), mi2 = __shfl(i2, src);
    if (lane < 8) {
        const float myv = (lane & 1) ? mv2 : mv1;
        const int   myi = (lane & 1) ? mi2 : mi1;
        out_idx[(size_t)token * 8 + lane] = (float)myi;
        out_w  [(size_t)token * 8 + lane] = myv * (2.5f / (sum + 1e-10f));
    }
}

extern "C" void kernel_launch(void* const* d_in, const int* in_sizes, int n_in,
                              void* d_out, int out_size, void* d_ws, size_t ws_size,
                              hipStream_t stream) {
    const float* H = (const float*)d_in[0];   // hidden_states [8192, 4096]
    const float* W = (const float*)d_in[1];   // gate_w        [256, 4096]

    float* out     = (float*)d_out;
    float* out_idx = out;                           // 8192*8
    float* out_w   = out + (size_t)N_TOKENS * 8;    // 8192*8
    float* logits  = out + (size_t)N_TOKENS * 16;   // 8192*256

    if (ws_size >= WS_NEED) {
        unsigned short* wsB = (unsigned short*)d_ws;
        float4* G = (float4*)((char*)d_ws + G_OFF_BYTES);
        static bool attr_done = []() {
            hipFuncSetAttribute((const void*)gate_fused,
                                hipFuncAttributeMaxDynamicSharedMemorySize,
                                (int)LDS_BYTES);
            return true;
        }();
        (void)attr_done;
        convert_w<<<dim3(512), dim3(256), 0, stream>>>(W, wsB);
        gate_fused<<<dim3(N_TOKENS / BM, 2), dim3(512), LDS_BYTES, stream>>>(
            H, wsB, logits, G);
        combine<<<dim3(N_TOKENS / 256), dim3(256), 0, stream>>>(G, out_idx, out_w);
    } else {
        gate_gemm_f32<<<dim3(N_TOKENS / FBM), dim3(256), 0, stream>>>(H, W, logits);
        topk_only<<<dim3(N_TOKENS / 4), dim3(256), 0, stream>>>(logits, out_idx, out_w);
    }
}

// Round 6
// 372.405 us; speedup vs baseline: 2.0685x; 2.0685x over previous
//
#include <hip/hip_runtime.h>
#include <math.h>

// Problem constants
constexpr int N_TOKENS = 8192;
constexpr int D_MODEL  = 4096;
constexpr int N_EXP    = 256;

// Tile: 64 tokens x 128 experts per block, grid (128, 2) = 256 blocks.
constexpr int BM = 64;
constexpr int BE = 128;
constexpr int BK = 32;              // K per chunk = MFMA K
constexpr int NC = D_MODEL / BK;    // 128 chunks

// ws B layout: [chunk][g8: 8 groups of 32 experts][plane hi/lo][32exp x 32k swizzled]
constexpr int WS_PLANE = 32 * 32;        // 1024 ushorts (2 KB)
constexpr int WS_GRP   = 2 * WS_PLANE;   // 2048
constexpr int WS_CHUNK = 8 * WS_GRP;     // 16384 (32 KB)
constexpr size_t WSB_USHORTS = (size_t)NC * WS_CHUNK;          // 2M ushorts = 4 MB
constexpr size_t G_OFF_BYTES = WSB_USHORTS * sizeof(unsigned short);
constexpr size_t WS_NEED = G_OFF_BYTES + (size_t)N_TOKENS * 4 * 16;  // + 512 KB side buf

// gate kernel LDS: 8 waves x 3 bufs x 2048 ushorts = 96 KB (epilogue Ct overlays)
constexpr int W_STRIDE = 3 * 2048;       // per-wave staging stride (ushorts)
constexpr size_t LDS_BYTES = 8 * W_STRIDE * sizeof(unsigned short);  // 98304

typedef __attribute__((ext_vector_type(8))) short short8;
typedef __attribute__((ext_vector_type(4))) float f32x4;
typedef unsigned int u32;
typedef const __attribute__((address_space(1))) u32* gas_ptr;
typedef __attribute__((address_space(3))) u32* las_ptr;

static __device__ __forceinline__ unsigned short f2bf(float x) {
    union { float f; unsigned u; } v; v.f = x;
    unsigned r = v.u + 0x7fffu + ((v.u >> 16) & 1u);   // RNE
    return (unsigned short)(r >> 16);
}
static __device__ __forceinline__ float bf2f(unsigned short s) {
    union { unsigned u; float f; } v; v.u = ((unsigned)s) << 16;
    return v.f;
}
static __device__ __forceinline__ unsigned fbits(float x) {
    union { float f; unsigned u; } v; v.f = x; return v.u;
}
static __device__ __forceinline__ float bitsf(unsigned u) {
    union { unsigned u; float f; } v; v.u = u; return v.f;
}

// ---- W fp32 -> bf16 hi/lo planes, chunk-major, granule-swizzled ----
__global__ __launch_bounds__(256) void convert_w(
    const float* __restrict__ W, unsigned short* __restrict__ wsB)
{
    const int id   = blockIdx.x * 256 + threadIdx.x;   // [0, 131072)
    const int c    = id >> 10;
    const int rem  = id & 1023;
    const int e    = rem >> 2;
    const int slot = rem & 3;
    const int kq   = slot ^ ((e >> 2) & 3);            // logical k-granule

    const float* src = W + (size_t)e * D_MODEL + c * BK + kq * 8;
    const float4 x0 = *(const float4*)src;
    const float4 x1 = *(const float4*)(src + 4);
    const float xs[8] = {x0.x, x0.y, x0.z, x0.w, x1.x, x1.y, x1.z, x1.w};
    short8 vh, vl;
    #pragma unroll
    for (int j = 0; j < 8; ++j) {
        const unsigned short h = f2bf(xs[j]);
        vh[j] = (short)h;
        vl[j] = (short)f2bf(xs[j] - bf2f(h));
    }
    unsigned short* dst = wsB + (size_t)c * WS_CHUNK + (e >> 5) * WS_GRP
                        + (e & 31) * 32 + slot * 8;
    *(short8*)dst              = vh;
    *(short8*)(dst + WS_PLANE) = vl;
}

#define STR2(x) #x
#define STR(x) STR2(x)

// ---- barrier-free bf16x3 MFMA GEMM + logits + per-group top2 ----
__global__ __launch_bounds__(512, 2) void gate_fused(
    const float* __restrict__ H, const unsigned short* __restrict__ wsB,
    float* __restrict__ logits, float4* __restrict__ G)
{
    extern __shared__ unsigned short lds[];

    const int t      = threadIdx.x;
    const int L      = t & 63;
    const int w      = t >> 6;          // wave 0..7
    const int mh     = w >> 2;          // token half (32 tokens)
    const int eq     = w & 3;           // expert quarter (32 experts)
    const int lane16 = L & 15;
    const int g4     = L >> 4;

    const int tok0 = blockIdx.x * BM;
    const int e0   = blockIdx.y * BE;
    const int g8   = blockIdx.y * 4 + eq;          // ws 32-expert group
    const int rowb = tok0 + mh * 32 + lane16;      // A fragment row base

    unsigned short* stg = lds + w * W_STRIDE;      // private staging (3 x 2048)

    f32x4 acc[2][2];
    #pragma unroll
    for (int mi = 0; mi < 2; ++mi)
        #pragma unroll
        for (int ni = 0; ni < 2; ++ni) acc[mi][ni] = (f32x4)0.0f;

    // depth-3 A prefetch; ALL indices compile-time constants (no scratch demotion)
    float4 araw[3][2][2];

    auto dmaB = [&](int c, int b) {                // b is a literal at every call site
        const unsigned short* src = wsB + (size_t)c * WS_CHUNK + g8 * WS_GRP;
        unsigned short* dst = stg + b * 2048;
        #pragma unroll
        for (int p = 0; p < 2; ++p)
            #pragma unroll
            for (int h = 0; h < 2; ++h) {
                const int o = p * 1024 + h * 512;
                __builtin_amdgcn_global_load_lds(
                    (gas_ptr)(const void*)(src + o + L * 8),
                    (las_ptr)(void*)(dst + o), 16, 0, 0);
            }
    };

    // NOTE: slot must be a literal at every call site.
    #define LOADA(c, slot)                                                          \
        do {                                                                        \
            _Pragma("unroll")                                                       \
            for (int mi = 0; mi < 2; ++mi) {                                        \
                const float* p = H + (size_t)(rowb + mi * 16) * D_MODEL             \
                               + (c) * BK + g4 * 8;                                 \
                araw[slot][mi][0] = *(const float4*)p;                              \
                araw[slot][mi][1] = *(const float4*)(p + 4);                        \
            }                                                                       \
        } while (0)

    // Prologue issue order (the vmcnt protocol depends on it):
    // dma0, A0, dma1, A1, A2  -> 20 vmem ops outstanding.
    dmaB(0, 0);
    asm volatile("" ::: "memory");
    LOADA(0, 0);
    asm volatile("" ::: "memory");
    dmaB(1, 1);
    asm volatile("" ::: "memory");
    LOADA(1, 1);
    asm volatile("" ::: "memory");
    LOADA(2, 2);

    int c = 0;
    // One chunk step. SLOT = c % 3 (literal). WAITN: outstanding left after wait.
    // Steady state: at top, outstanding (old->new) = A(c),dma(c),A(c+1),dma(c+1),A(c+2)
    // = 20 ops; retiring A(c)+dma(c) leaves 12.
    #define BODY(SLOT, WAITN)                                                       \
    do {                                                                            \
        asm volatile("s_barrier" ::: "memory"); /* pacing only; no vmcnt drain */   \
        asm volatile("s_waitcnt vmcnt(" STR(WAITN) ")" ::: "memory");               \
        /* convert A(c): fp32 -> bf16 hi (trunc) + lo residual */                   \
        short8 ah[2], al[2];                                                        \
        _Pragma("unroll")                                                           \
        for (int mi = 0; mi < 2; ++mi) {                                            \
            float xs[8];                                                            \
            _Pragma("unroll")                                                       \
            for (int hf = 0; hf < 2; ++hf) {                                        \
                const float4 v = araw[SLOT][mi][hf];                                \
                xs[hf * 4 + 0] = v.x; xs[hf * 4 + 1] = v.y;                         \
                xs[hf * 4 + 2] = v.z; xs[hf * 4 + 3] = v.w;                         \
            }                                                                       \
            union { short8 s; u32 u[4]; } Hh, Ll;                                   \
            _Pragma("unroll")                                                       \
            for (int j = 0; j < 4; ++j) {                                           \
                const u32 b0 = fbits(xs[2 * j]), b1 = fbits(xs[2 * j + 1]);         \
                const u32 h0 = b0 & 0xFFFF0000u, h1 = b1 & 0xFFFF0000u;             \
                Hh.u[j] = (b0 >> 16) | h1;                                          \
                const float l0 = xs[2 * j] - bitsf(h0);                             \
                const float l1 = xs[2 * j + 1] - bitsf(h1);                         \
                Ll.u[j] = (fbits(l0) >> 16) | (fbits(l1) & 0xFFFF0000u);            \
            }                                                                       \
            ah[mi] = Hh.s; al[mi] = Ll.s;                                           \
        }                                                                           \
        /* B fragments from private staging buffer SLOT */                          \
        const unsigned short* bb = stg + (SLOT) * 2048;                             \
        short8 bh[2], bl[2];                                                        \
        _Pragma("unroll")                                                           \
        for (int ni = 0; ni < 2; ++ni) {                                            \
            const int e_loc = ni * 16 + lane16;                                     \
            const int off   = e_loc * 32 + ((g4 ^ ((e_loc >> 2) & 3)) << 3);        \
            bh[ni] = *(const short8*)(bb + off);                                    \
            bl[ni] = *(const short8*)(bb + 1024 + off);                             \
        }                                                                           \
        /* deep prefetch; order dma THEN loadA is load-bearing for vmcnt */         \
        if (c + 2 < NC) dmaB(c + 2, ((SLOT) + 2) % 3);                              \
        asm volatile("" ::: "memory");                                              \
        if (c + 3 < NC) LOADA(c + 3, SLOT);                                         \
        /* 12 MFMAs, term-major so each acc is revisited at distance 4 */           \
        _Pragma("unroll")                                                           \
        for (int ni = 0; ni < 2; ++ni)                                              \
            _Pragma("unroll")                                                       \
            for (int mi = 0; mi < 2; ++mi)                                          \
                acc[mi][ni] = __builtin_amdgcn_mfma_f32_16x16x32_bf16(              \
                    ah[mi], bh[ni], acc[mi][ni], 0, 0, 0);                          \
        _Pragma("unroll")                                                           \
        for (int ni = 0; ni < 2; ++ni)                                              \
            _Pragma("unroll")                                                       \
            for (int mi = 0; mi < 2; ++mi)                                          \
                acc[mi][ni] = __builtin_amdgcn_mfma_f32_16x16x32_bf16(              \
                    ah[mi], bl[ni], acc[mi][ni], 0, 0, 0);                          \
        _Pragma("unroll")                                                           \
        for (int ni = 0; ni < 2; ++ni)                                              \
            _Pragma("unroll")                                                       \
            for (int mi = 0; mi < 2; ++mi)                                          \
                acc[mi][ni] = __builtin_amdgcn_mfma_f32_16x16x32_bf16(              \
                    al[mi], bh[ni], acc[mi][ni], 0, 0, 0);                          \
        ++c;                                                                        \
    } while (0)

    // 42 triples cover c = 0..125 (NC-3 = 125 is the last vmcnt(12) step)
    for (int it = 0; it < 42; ++it) {
        BODY(0, 12);
        BODY(1, 12);
        BODY(2, 12);
    }
    BODY(0, 8);   // c = 126
    BODY(1, 0);   // c = 127

    #undef BODY
    #undef LOADA

    // ---- epilogue ----
    __syncthreads();                     // staging dead everywhere after this
    float* Ct = (float*)lds;             // [64][132] fp32 = 33.8 KB overlay
    #pragma unroll
    for (int mi = 0; mi < 2; ++mi)
        #pragma unroll
        for (int ni = 0; ni < 2; ++ni)
            #pragma unroll
            for (int r = 0; r < 4; ++r) {
                const int tk  = mh * 32 + mi * 16 + g4 * 4 + r;   // C/D row
                const int col = eq * 32 + ni * 16 + lane16;        // C/D col
                Ct[tk * 132 + col] = acc[mi][ni][r];
            }
    __syncthreads();

    // coalesced logits store: 64 rows x 128 cols = 2048 float4 / 512 thr
    #pragma unroll
    for (int i = 0; i < 4; ++i) {
        const int id = i * 512 + t;
        const int tk = id >> 5, j = id & 31;
        *(float4*)(logits + (size_t)(tok0 + tk) * N_EXP + e0 + j * 4) =
            *(const float4*)(Ct + tk * 132 + j * 4);
    }

    // per-(token, 64-expert-group) top2 on raw logits; sigmoid on winners only
    for (int it = 0; it < 16; ++it) {
        const int u  = w * 16 + it;
        const int tk = u >> 1, gl = u & 1;
        float v1 = Ct[tk * 132 + gl * 64 + L];
        int   i1 = e0 + gl * 64 + L;
        float v2 = -3.0e38f;
        int   i2 = i1;
        #pragma unroll
        for (int off = 1; off < 64; off <<= 1) {
            const float ov1 = __shfl_xor(v1, off);
            const int   oi1 = __shfl_xor(i1, off);
            const float ov2 = __shfl_xor(v2, off);
            const int   oi2 = __shfl_xor(i2, off);
            const bool o1_beats_m1 = (ov1 > v1) || (ov1 == v1 && oi1 < i1);
            if (o1_beats_m1) {
                const bool m1_beats_o2 = (v1 > ov2) || (v1 == ov2 && i1 < oi2);
                const float nv2 = m1_beats_o2 ? v1 : ov2;
                const int   ni2 = m1_beats_o2 ? i1 : oi2;
                v1 = ov1; i1 = oi1; v2 = nv2; i2 = ni2;
            } else {
                const bool o1_beats_m2 = (ov1 > v2) || (ov1 == v2 && oi1 < i2);
                v2 = o1_beats_m2 ? ov1 : v2;
                i2 = o1_beats_m2 ? oi1 : i2;
            }
        }
        if (L == 0) {
            const float s1 = 1.0f / (1.0f + expf(-v1));
            const float s2 = 1.0f / (1.0f + expf(-v2));
            float4 r; r.x = s1; r.y = s2; r.z = (float)i1; r.w = (float)i2;
            G[(size_t)(tok0 + tk) * 4 + (e0 >> 6) + gl] = r;
        }
    }
}

// ---- combine per-group top2 -> normalized weights + indices ----
__global__ __launch_bounds__(256) void combine(
    const float4* __restrict__ G,
    float* __restrict__ out_idx, float* __restrict__ out_w)
{
    const int tok = blockIdx.x * 256 + threadIdx.x;
    float4 g[4];
    #pragma unroll
    for (int i = 0; i < 4; ++i) g[i] = G[(size_t)tok * 4 + i];
    float sum = 0.0f;
    #pragma unroll
    for (int i = 0; i < 4; ++i) sum += g[i].x + g[i].y;
    const float sc = 2.5f / (sum + 1e-10f);
    float4 i01, i23, w01, w23;
    i01.x = g[0].z; i01.y = g[0].w; i01.z = g[1].z; i01.w = g[1].w;
    i23.x = g[2].z; i23.y = g[2].w; i23.z = g[3].z; i23.w = g[3].w;
    w01.x = g[0].x * sc; w01.y = g[0].y * sc; w01.z = g[1].x * sc; w01.w = g[1].y * sc;
    w23.x = g[2].x * sc; w23.y = g[2].y * sc; w23.z = g[3].x * sc; w23.w = g[3].y * sc;
    ((float4*)out_idx)[(size_t)tok * 2]     = i01;
    ((float4*)out_idx)[(size_t)tok * 2 + 1] = i23;
    ((float4*)out_w)[(size_t)tok * 2]       = w01;
    ((float4*)out_w)[(size_t)tok * 2 + 1]   = w23;
}

// ---------------- fallback (ws too small): fp32 VALU path ----------------
constexpr int FBM = 32;
constexpr int FBK = 16;
constexpr int FNC = D_MODEL / FBK;

__global__ __launch_bounds__(256) void gate_gemm_f32(
    const float* __restrict__ H, const float* __restrict__ W,
    float* __restrict__ logits)
{
    __shared__ float As[2][FBK][FBM + 4];
    __shared__ float Bs[2][FBK][N_EXP + 1];
    const int t = threadIdx.x, tx = t & 31, ty = t >> 5;
    const int tok0 = blockIdx.x * FBM, tokA = t >> 2, kqA = t & 3;
    float4 pa, pb[4];
    float acc[4][8];
    #pragma unroll
    for (int i = 0; i < 4; ++i)
        #pragma unroll
        for (int j = 0; j < 8; ++j) acc[i][j] = 0.0f;
    auto issue_loads = [&](int kc) {
        if (t < 128) pa = *(const float4*)(H + (size_t)(tok0 + tokA) * D_MODEL + kc + kqA * 4);
        #pragma unroll
        for (int j = 0; j < 4; ++j) {
            const int flat = t + 256 * j, e = flat >> 2, kq = flat & 3;
            pb[j] = *(const float4*)(W + (size_t)e * D_MODEL + kc + kq * 4);
        }
    };
    auto write_lds = [&](int buf) {
        if (t < 128) {
            As[buf][kqA * 4 + 0][tokA] = pa.x; As[buf][kqA * 4 + 1][tokA] = pa.y;
            As[buf][kqA * 4 + 2][tokA] = pa.z; As[buf][kqA * 4 + 3][tokA] = pa.w;
        }
        #pragma unroll
        for (int j = 0; j < 4; ++j) {
            const int flat = t + 256 * j, e = flat >> 2, kq = flat & 3;
            Bs[buf][kq * 4 + 0][e] = pb[j].x; Bs[buf][kq * 4 + 1][e] = pb[j].y;
            Bs[buf][kq * 4 + 2][e] = pb[j].z; Bs[buf][kq * 4 + 3][e] = pb[j].w;
        }
    };
    issue_loads(0); write_lds(0); __syncthreads();
    for (int c = 0; c < FNC; ++c) {
        const int buf = c & 1;
        if (c + 1 < FNC) issue_loads((c + 1) * FBK);
        #pragma unroll
        for (int k = 0; k < FBK; ++k) {
            const float4 av = *(const float4*)&As[buf][k][ty * 4];
            const float a[4] = {av.x, av.y, av.z, av.w};
            float b[8];
            #pragma unroll
            for (int j = 0; j < 8; ++j) b[j] = Bs[buf][k][tx + 32 * j];
            #pragma unroll
            for (int i = 0; i < 4; ++i)
                #pragma unroll
                for (int j = 0; j < 8; ++j) acc[i][j] = fmaf(a[i], b[j], acc[i][j]);
        }
        if (c + 1 < FNC) write_lds(buf ^ 1);
        __syncthreads();
    }
    #pragma unroll
    for (int i = 0; i < 4; ++i) {
        const size_t row = (size_t)(tok0 + ty * 4 + i) * N_EXP;
        #pragma unroll
        for (int j = 0; j < 8; ++j) logits[row + tx + 32 * j] = acc[i][j];
    }
}

__global__ __launch_bounds__(256) void topk_only(
    const float* __restrict__ logits,
    float* __restrict__ out_idx, float* __restrict__ out_w)
{
    const int token = blockIdx.x * 4 + (threadIdx.x >> 6);
    const int lane  = threadIdx.x & 63;
    const float4 x = *(const float4*)(logits + (size_t)token * N_EXP + lane * 4);
    float sc[4];
    sc[0] = 1.0f / (1.0f + expf(-x.x)); sc[1] = 1.0f / (1.0f + expf(-x.y));
    sc[2] = 1.0f / (1.0f + expf(-x.z)); sc[3] = 1.0f / (1.0f + expf(-x.w));
    float v1 = -1.0f, v2 = -1.0f; int i1 = 0, i2 = 0;
    #pragma unroll
    for (int j = 0; j < 4; ++j) {
        const int idx = lane * 4 + j;
        if (sc[j] > v1)      { v2 = v1; i2 = i1; v1 = sc[j]; i1 = idx; }
        else if (sc[j] > v2) { v2 = sc[j]; i2 = idx; }
    }
    #pragma unroll
    for (int offx = 1; offx < 16; offx <<= 1) {
        const float ov1 = __shfl_xor(v1, offx); const int oi1 = __shfl_xor(i1, offx);
        const float ov2 = __shfl_xor(v2, offx); const int oi2 = __shfl_xor(i2, offx);
        const bool o1_beats_m1 = (ov1 > v1) || (ov1 == v1 && oi1 < i1);
        if (o1_beats_m1) {
            const bool m1_beats_o2 = (v1 > ov2) || (v1 == ov2 && i1 < oi2);
            const float nv2 = m1_beats_o2 ? v1 : ov2;
            const int   ni2 = m1_beats_o2 ? i1 : oi2;
            v1 = ov1; i1 = oi1; v2 = nv2; i2 = ni2;
        } else {
            const bool o1_beats_m2 = (ov1 > v2) || (ov1 == v2 && oi1 < i2);
            v2 = o1_beats_m2 ? ov1 : v2; i2 = o1_beats_m2 ? oi1 : i2;
        }
    }
    float sum = 0.0f;
    #pragma unroll
    for (int g = 0; g < 4; ++g) sum += __shfl(v1, g * 16) + __shfl(v2, g * 16);
    const int src = ((lane >> 1) & 3) * 16;
    const float mv1 = __shfl(v1, src), mv2 = __shfl(v2, src);
    const int   mi1 = __shfl(i1, src), mi2 = __shfl(i2, src);
    if (lane < 8) {
        const float myv = (lane & 1) ? mv2 : mv1;
        const int   myi = (lane & 1) ? mi2 : mi1;
        out_idx[(size_t)token * 8 + lane] = (float)myi;
        out_w  [(size_t)token * 8 + lane] = myv * (2.5f / (sum + 1e-10f));
    }
}

extern "C" void kernel_launch(void* const* d_in, const int* in_sizes, int n_in,
                              void* d_out, int out_size, void* d_ws, size_t ws_size,
                              hipStream_t stream) {
    const float* H = (const float*)d_in[0];   // hidden_states [8192, 4096]
    const float* W = (const float*)d_in[1];   // gate_w        [256, 4096]

    float* out     = (float*)d_out;
    float* out_idx = out;                           // 8192*8
    float* out_w   = out + (size_t)N_TOKENS * 8;    // 8192*8
    float* logits  = out + (size_t)N_TOKENS * 16;   // 8192*256

    if (ws_size >= WS_NEED) {
        unsigned short* wsB = (unsigned short*)d_ws;
        float4* G = (float4*)((char*)d_ws + G_OFF_BYTES);
        static bool attr_done = []() {
            hipFuncSetAttribute((const void*)gate_fused,
                                hipFuncAttributeMaxDynamicSharedMemorySize,
                                (int)LDS_BYTES);
            return true;
        }();
        (void)attr_done;
        convert_w<<<dim3(512), dim3(256), 0, stream>>>(W, wsB);
        gate_fused<<<dim3(N_TOKENS / BM, 2), dim3(512), LDS_BYTES, stream>>>(
            H, wsB, logits, G);
        combine<<<dim3(N_TOKENS / 256), dim3(256), 0, stream>>>(G, out_idx, out_w);
    } else {
        gate_gemm_f32<<<dim3(N_TOKENS / FBM), dim3(256), 0, stream>>>(H, W, logits);
        topk_only<<<dim3(N_TOKENS / 4), dim3(256), 0, stream>>>(logits, out_idx, out_w);
    }
}